// Round 6
// baseline (156.532 us; speedup 1.0000x reference)
//
#include <hip/hip_runtime.h>
#include <math.h>

#define E_TOT 262144
#define LDIM  128
#define XPB   272            // X row pitch in bytes
#define MIN_VARF 0.001f
#define INV_SQRT2PIF 0.3989422804014327f
#define NBLK  (E_TOT / 64)   // 4096 blocks

typedef _Float16 half8 __attribute__((ext_vector_type(8)));
typedef float    f32x4 __attribute__((ext_vector_type(4)));
typedef float    f32x2 __attribute__((ext_vector_type(2)));

// ---- d_ws byte layout ----
#define BIAS_OFF  256      // 3 layers x 128 f32 (reordered [g*32+t*4+r])
#define WOUT_OFF  1792     // 2 x 128 f32 (W_out row0, W_out row0^2; reordered)
#define BOUT_OFF  2816     // 1 f32
#define PK_L0     4096     // 5 ksteps * 8 tiles * 64 lanes * 16 B = 40960
#define PK_L1     45056    // 4 ksteps * 8192 = 32768
#define PK_L2     77824    // 32768 -> end 110592
#define PART_OFF  110592   // NBLK x float2 per-block partials (al, loss) = 32768 B

__device__ __forceinline__ short h2s(float x) {
    union U { _Float16 h; short s; } u; u.h = (_Float16)x; return u.s;
}

// lean ADF-ReLU: rsq-based sqrt/div, native exp, Winitzki erf (abs err ~1.3e-4)
__device__ __forceinline__ void adf_relu(float& m, float& v) {
    float vv = fmaxf(v, 1e-6f);
    float is = __builtin_amdgcn_rsqf(vv);    // 1/sd
    float sd = vv * is;                      // sqrt(vv)
    float r  = m * is;
    float qq = 0.5f * r * r;                 // u^2, u = r/sqrt(2)
    float sp = sd * __expf(-qq) * INV_SQRT2PIF;   // sd * pdf
    const float A = 0.147f;
    float aq  = A * qq;
    float num = qq * (1.27323954f + aq);     // u^2*(4/pi + a u^2)
    float den = 1.0f + aq;
    float z   = -num * __builtin_amdgcn_rcpf(den);
    float wv  = 1.0f - __expf(z);
    float s   = wv * __builtin_amdgcn_rsqf(fmaxf(wv, 1e-20f));  // sqrt(wv)
    float serf = copysignf(s, m);
    float cdf  = 0.5f + 0.5f * serf;
    float mo = fmaf(m, cdf, sp);
    float vo = fmaf(fmaf(m, m, vv), cdf, fmaf(m, sp, -mo * mo));
    m = mo; v = vo;
}

// Pack W (mean path only) into fragment-linear f16:
// entry (ks*8 + t)*64 + lane holds A[row = 16t + (lane&15)][k = 32ks + 8*(lane>>4) + j]
__global__ void prep(const float* __restrict__ W_in, const float* __restrict__ b_in,
                     const float* __restrict__ W1,   const float* __restrict__ b1,
                     const float* __restrict__ W2,   const float* __restrict__ b2,
                     const float* __restrict__ W_out,const float* __restrict__ b_out,
                     char* __restrict__ ws)
{
    int idx = blockIdx.x * 256 + threadIdx.x;
    if (idx < 6656) {
        const float* W; int Kfull; long dstoff; int entry;
        if (idx < 2560)      { entry = idx;        W = W_in; Kfull = 131; dstoff = PK_L0; }
        else if (idx < 4608) { entry = idx - 2560; W = W1;   Kfull = 128; dstoff = PK_L1; }
        else                 { entry = idx - 4608; W = W2;   Kfull = 128; dstoff = PK_L2; }
        int ks   = entry >> 9;
        int rest = entry & 511;
        int t    = rest >> 6;
        int lane = rest & 63;
        int rowi = t * 16 + (lane & 15);
        int k0   = ks * 32 + (lane >> 4) * 8;
        half8 hv;
#pragma unroll
        for (int j = 0; j < 8; ++j) {
            int k = k0 + j;
            hv[j] = (_Float16)((k < Kfull) ? W[rowi * Kfull + k] : 0.0f);
        }
        *(half8*)(ws + dstoff + (long)entry * 16) = hv;
    } else if (idx < 6656 + 384) {
        int j = idx - 6656; int layer = j >> 7; int pidx = j & 127;
        int gg = pidx >> 5, t = (pidx >> 2) & 7, r = pidx & 3;
        int n = t * 16 + gg * 4 + r;
        const float* b = layer == 0 ? b_in : (layer == 1 ? b1 : b2);
        ((float*)(ws + BIAS_OFF))[layer * 128 + pidx] = b[n];
    } else if (idx < 6656 + 384 + 256) {
        int j = idx - 6656 - 384; int path = j >> 7; int pidx = j & 127;
        int gg = pidx >> 5, t = (pidx >> 2) & 7, r = pidx & 3;
        int n = t * 16 + gg * 4 + r;
        float v = W_out[n];
        if (path) v = v * v;
        ((float*)(ws + WOUT_OFF))[path * 128 + pidx] = v;
    } else if (idx == 6656 + 384 + 256) {
        ((float*)(ws + BOUT_OFF))[0] = b_out[0];
    }
}

__global__ void __launch_bounds__(256, 3)
interp_main(const float* __restrict__ pos_source, const float* __restrict__ pos_target,
            const float* __restrict__ latents,    const float* __restrict__ varr,
            const float* __restrict__ drop_mask,
            const int* __restrict__ row, const int* __restrict__ col, const int* __restrict__ occ,
            float* __restrict__ out, char* __restrict__ ws)
{
    __shared__ __align__(16) short Xm[64][XPB / 2];
    __shared__ __align__(16) short Xv[64][XPB / 2];
    __shared__ float wred[4][2];

    const int tid  = threadIdx.x;
    const int lane = tid & 63;
    const int w    = tid >> 6;
    const int q    = lane & 15;
    const int g    = lane >> 4;
    const int erow = w * 16 + q;
    const int gbase = blockIdx.x * 64;
    const int ge   = gbase + erow;
    char* xmb = (char*)&Xm[0][0];
    char* xvb = (char*)&Xv[0][0];

    // ---- prefetch: mask (nt, needed last) -> regs; occ, pos_rel, L0 B-fragments ----
    f32x4 md[8];
    {
        const f32x4* dmp = (const f32x4*)drop_mask + (size_t)ge * 32 + g;
#pragma unroll
        for (int t = 0; t < 8; ++t) md[t] = __builtin_nontemporal_load(dmp + t * 4);
    }
    const int c0 = col[ge];
    const int r0 = row[ge];
    const float occf = (float)occ[r0];
    const float px = pos_target[r0 * 3 + 0] - pos_source[c0 * 3 + 0];
    const float py = pos_target[r0 * 3 + 1] - pos_source[c0 * 3 + 1];
    const float pz = pos_target[r0 * 3 + 2] - pos_source[c0 * 3 + 2];

    half8 bm4[4], bv4[4];
    {
        const float* lm = latents + (long)c0 * LDIM;
        const float* lv = varr    + (long)c0 * LDIM;
#pragma unroll
        for (int ks = 0; ks < 4; ++ks) {
            const f32x4* am4 = (const f32x4*)(lm + ks * 32 + g * 8);
            const f32x4* av4 = (const f32x4*)(lv + ks * 32 + g * 8);
            f32x4 fm0 = am4[0], fm1 = am4[1];
            f32x4 fv0 = av4[0], fv1 = av4[1];
            half8 bm, bv;
#pragma unroll
            for (int j = 0; j < 4; ++j) {
                bm[j] = (_Float16)fm0[j]; bm[j + 4] = (_Float16)fm1[j];
                bv[j] = (_Float16)fv0[j]; bv[j + 4] = (_Float16)fv1[j];
            }
            bm4[ks] = bm; bv4[ks] = bv;
        }
    }

    f32x4 accm[8], accv[8];
    const f32x4 zz = {0.0f, 0.0f, 0.0f, 0.0f};
#pragma unroll
    for (int t = 0; t < 8; ++t) { accm[t] = zz; accv[t] = zz; }

    // ================= layer 0: B from regs, A from global (L1/L2-hot) =================
    {
        const char* pk = ws + PK_L0 + lane * 16;
#pragma unroll
        for (int ks = 0; ks < 4; ++ks) {
            const char* pmk = pk + ks * 8192;
            half8 bm = bm4[ks], bv = bv4[ks];
#pragma unroll
            for (int t = 0; t < 8; ++t) {
                half8 am = *(const half8*)(pmk + t * 1024);
                half8 av = am * am;
                accm[t] = __builtin_amdgcn_mfma_f32_16x16x32_f16(am, bm, accm[t], 0, 0, 0);
                accv[t] = __builtin_amdgcn_mfma_f32_16x16x32_f16(av, bv, accv[t], 0, 0, 0);
            }
        }
        half8 bpos = {(_Float16)0.f, (_Float16)0.f, (_Float16)0.f, (_Float16)0.f,
                      (_Float16)0.f, (_Float16)0.f, (_Float16)0.f, (_Float16)0.f};
        if (g == 0) { bpos[0] = (_Float16)px; bpos[1] = (_Float16)py; bpos[2] = (_Float16)pz; }
        const char* pmk = pk + 4 * 8192;
#pragma unroll
        for (int t = 0; t < 8; ++t) {
            half8 am = *(const half8*)(pmk + t * 1024);
            half8 av = am * am;
            accm[t] = __builtin_amdgcn_mfma_f32_16x16x32_f16(am, bpos, accm[t], 0, 0, 0);
            accv[t] = __builtin_amdgcn_mfma_f32_16x16x32_f16(av, bpos, accv[t], 0, 0, 0);
        }
        // epilogue 0: bias + adf_relu -> X LDS (wave-private rows, no barrier)
        const f32x4* bp = (const f32x4*)(ws + BIAS_OFF) + g * 8;
#pragma unroll
        for (int t = 0; t < 8; ++t) {
            f32x4 b4 = bp[t];
            float m0 = accm[t][0] + b4[0], m1 = accm[t][1] + b4[1];
            float m2 = accm[t][2] + b4[2], m3 = accm[t][3] + b4[3];
            float v0 = accv[t][0], v1 = accv[t][1], v2 = accv[t][2], v3 = accv[t][3];
            adf_relu(m0, v0); adf_relu(m1, v1); adf_relu(m2, v2); adf_relu(m3, v3);
            short4 sm; sm.x = h2s(m0); sm.y = h2s(m1); sm.z = h2s(m2); sm.w = h2s(m3);
            short4 sv; sv.x = h2s(v0); sv.y = h2s(v1); sv.z = h2s(v2); sv.w = h2s(v3);
            *(short4*)(xmb + erow * XPB + t * 32 + g * 8) = sm;
            *(short4*)(xvb + erow * XPB + t * 32 + g * 8) = sv;
        }
    }

    // ================= layer 1: B from X LDS, A from global =================
#pragma unroll
    for (int t = 0; t < 8; ++t) { accm[t] = zz; accv[t] = zz; }
    {
        const char* pk = ws + PK_L1 + lane * 16;
#pragma unroll
        for (int ks = 0; ks < 4; ++ks) {
            half8 bm = *(const half8*)(xmb + erow * XPB + ks * 64 + g * 16);
            half8 bv = *(const half8*)(xvb + erow * XPB + ks * 64 + g * 16);
            const char* pmk = pk + ks * 8192;
#pragma unroll
            for (int t = 0; t < 8; ++t) {
                half8 am = *(const half8*)(pmk + t * 1024);
                half8 av = am * am;
                accm[t] = __builtin_amdgcn_mfma_f32_16x16x32_f16(am, bm, accm[t], 0, 0, 0);
                accv[t] = __builtin_amdgcn_mfma_f32_16x16x32_f16(av, bv, accv[t], 0, 0, 0);
            }
        }
        const f32x4* bp = (const f32x4*)(ws + BIAS_OFF) + 32 + g * 8;
#pragma unroll
        for (int t = 0; t < 8; ++t) {
            f32x4 b4 = bp[t];
            float m0 = accm[t][0] + b4[0], m1 = accm[t][1] + b4[1];
            float m2 = accm[t][2] + b4[2], m3 = accm[t][3] + b4[3];
            float v0 = accv[t][0], v1 = accv[t][1], v2 = accv[t][2], v3 = accv[t][3];
            adf_relu(m0, v0); adf_relu(m1, v1); adf_relu(m2, v2); adf_relu(m3, v3);
            short4 sm; sm.x = h2s(m0); sm.y = h2s(m1); sm.z = h2s(m2); sm.w = h2s(m3);
            short4 sv; sv.x = h2s(v0); sv.y = h2s(v1); sv.z = h2s(v2); sv.w = h2s(v3);
            *(short4*)(xmb + erow * XPB + t * 32 + g * 8) = sm;
            *(short4*)(xvb + erow * XPB + t * 32 + g * 8) = sv;
        }
    }

    // ================= layer 2: B from X LDS, A from global =================
#pragma unroll
    for (int t = 0; t < 8; ++t) { accm[t] = zz; accv[t] = zz; }
    {
        const char* pk = ws + PK_L2 + lane * 16;
#pragma unroll
        for (int ks = 0; ks < 4; ++ks) {
            half8 bm = *(const half8*)(xmb + erow * XPB + ks * 64 + g * 16);
            half8 bv = *(const half8*)(xvb + erow * XPB + ks * 64 + g * 16);
            const char* pmk = pk + ks * 8192;
#pragma unroll
            for (int t = 0; t < 8; ++t) {
                half8 am = *(const half8*)(pmk + t * 1024);
                half8 av = am * am;
                accm[t] = __builtin_amdgcn_mfma_f32_16x16x32_f16(am, bm, accm[t], 0, 0, 0);
                accv[t] = __builtin_amdgcn_mfma_f32_16x16x32_f16(av, bv, accv[t], 0, 0, 0);
            }
        }
    }

    // ================= final epilogue: dropout + W_out dot + reductions =================
    {
        float pmacc = 0.0f, pvacc = 0.0f;
        const f32x4* wmp = (const f32x4*)(ws + WOUT_OFF);
        const f32x4* bp  = (const f32x4*)(ws + BIAS_OFF) + 64 + g * 8;
#pragma unroll
        for (int t = 0; t < 8; ++t) {
            f32x4 b4 = bp[t];
            f32x4 d4 = md[t];
            f32x4 w4 = wmp[g * 8 + t];
            f32x4 s4 = wmp[32 + g * 8 + t];
            float m0 = (accm[t][0] + b4[0]) * d4[0];
            float m1 = (accm[t][1] + b4[1]) * d4[1];
            float m2 = (accm[t][2] + b4[2]) * d4[2];
            float m3 = (accm[t][3] + b4[3]) * d4[3];
            float v0 = accv[t][0] * d4[0] * d4[0] + MIN_VARF;
            float v1 = accv[t][1] * d4[1] * d4[1] + MIN_VARF;
            float v2 = accv[t][2] * d4[2] * d4[2] + MIN_VARF;
            float v3 = accv[t][3] * d4[3] * d4[3] + MIN_VARF;
            pmacc += w4[0] * m0 + w4[1] * m1 + w4[2] * m2 + w4[3] * m3;
            pvacc += s4[0] * v0 + s4[1] * v1 + s4[2] * v2 + s4[3] * v3;
        }
        pmacc += __shfl_xor(pmacc, 16, 64);
        pmacc += __shfl_xor(pmacc, 32, 64);
        pvacc += __shfl_xor(pvacc, 16, 64);
        pvacc += __shfl_xor(pvacc, 32, 64);
        float bout = *(const float*)(ws + BOUT_OFF);
        float p = pmacc + bout;
        if (lane < 16) {
            out[ge] = p;
            out[E_TOT + 2 + ge] = occf;
        }
        float a = fabsf(p);
        float loss = fmaxf(p, 0.0f) - p * occf + __logf(1.0f + __expf(-a));
        float al = fabsf(pvacc);
#pragma unroll
        for (int off = 1; off < 16; off <<= 1) {
            al   += __shfl_xor(al, off, 64);
            loss += __shfl_xor(loss, off, 64);
        }
        if (lane == 0) { wred[w][0] = al; wred[w][1] = loss; }
    }
    __syncthreads();
    if (tid == 0) {
        f32x2 s;
        s[0] = wred[0][0] + wred[1][0] + wred[2][0] + wred[3][0];
        s[1] = wred[0][1] + wred[1][1] + wred[2][1] + wred[3][1];
        *((f32x2*)(ws + PART_OFF) + blockIdx.x) = s;   // plain store, no atomics
    }
}

__global__ void __launch_bounds__(256)
interp_finalize(const char* __restrict__ ws, float* __restrict__ out)
{
    __shared__ float sal[4], sls[4];
    const int tid  = threadIdx.x;
    const int lane = tid & 63;
    const int w    = tid >> 6;
    float al = 0.0f, ls = 0.0f;
    const f32x2* part = (const f32x2*)(ws + PART_OFF);
    for (int i = tid; i < NBLK; i += 256) {
        f32x2 p = part[i];
        al += p[0]; ls += p[1];
    }
#pragma unroll
    for (int off = 1; off < 64; off <<= 1) {
        al += __shfl_xor(al, off, 64);
        ls += __shfl_xor(ls, off, 64);
    }
    if (lane == 0) { sal[w] = al; sls[w] = ls; }
    __syncthreads();
    if (tid == 0) {
        const float inv = 1.0f / (float)E_TOT;
        out[E_TOT]     = (sal[0] + sal[1] + sal[2] + sal[3]) * inv;
        out[E_TOT + 1] = (sls[0] + sls[1] + sls[2] + sls[3]) * inv;
    }
}

extern "C" void kernel_launch(void* const* d_in, const int* in_sizes, int n_in,
                              void* d_out, int out_size, void* d_ws, size_t ws_size,
                              hipStream_t stream) {
    (void)in_sizes; (void)n_in; (void)out_size; (void)ws_size;
    const float* pos_source = (const float*)d_in[0];
    const float* pos_target = (const float*)d_in[1];
    const float* latents    = (const float*)d_in[2];
    const float* varr       = (const float*)d_in[3];
    const float* drop_mask  = (const float*)d_in[4];
    const float* W_in       = (const float*)d_in[5];
    const float* b_in       = (const float*)d_in[6];
    const float* W1         = (const float*)d_in[7];
    const float* b1         = (const float*)d_in[8];
    const float* W2         = (const float*)d_in[9];
    const float* b2         = (const float*)d_in[10];
    const float* W_out      = (const float*)d_in[11];
    const float* b_out      = (const float*)d_in[12];
    const int*   row        = (const int*)d_in[13];
    const int*   col        = (const int*)d_in[14];
    const int*   occ        = (const int*)d_in[15];
    float* out = (float*)d_out;
    char*  ws  = (char*)d_ws;

    prep<<<29, 256, 0, stream>>>(W_in, b_in, W1, b1, W2, b2, W_out, b_out, ws);
    interp_main<<<NBLK, 256, 0, stream>>>(
        pos_source, pos_target, latents, varr, drop_mask,
        row, col, occ, out, ws);
    interp_finalize<<<1, 256, 0, stream>>>(ws, out);
}